// Round 2
// baseline (303.482 us; speedup 1.0000x reference)
//
#include <hip/hip_runtime.h>
#include <hip/hip_bf16.h>

// Problem: B=4, S=2048, D=1024 attention layer, fp32 in/out, bf16 MFMA compute.
// Pipeline: cvt_x -> transpose_w -> 3x proj GEMM (v stored transposed) ->
//           scores GEMM (*1/32) -> row softmax -> PV GEMM -> fp32 out.
// All GEMMs are NT-form (A [M][K], B [N][K], K contiguous), m97 128^2 structure.
//
// ws layout (bytes):
//   xb   @ 0         : bf16 [8192][1024]        (16 MB)
//   wt   @ 16777216  : bf16 [3][1024][1024]     (6 MB)   order k,q,v ([n][k] transposed)
//   kb   @ 23068672  : bf16 [4][2048][1024]     (16 MB)
//   qb   @ 39845888  : bf16 [4][2048][1024]     (16 MB)
//   vtb  @ 56623104  : bf16 [4][1024][2048]     (16 MB)  (per-batch transposed V)
//   sc   @ 73400320  : bf16 [4][2048][2048]     (32 MB)  scores, softmaxed in place
// total ~102 MB

typedef __attribute__((ext_vector_type(8))) short short8;
typedef __attribute__((ext_vector_type(4))) float f32x4;

__device__ __forceinline__ unsigned short f2b(float f) {
    unsigned u = __builtin_bit_cast(unsigned, f);
    unsigned r = 0x7FFFu + ((u >> 16) & 1u);
    return (unsigned short)((u + r) >> 16);
}
__device__ __forceinline__ float b2f(unsigned short h) {
    return __builtin_bit_cast(float, ((unsigned)h) << 16);
}

// async global->LDS, 16B per lane. lds dest must be wave-uniform base (+lane*16 implicit).
__device__ __forceinline__ void gload16(const void* g, void* lds_uniform_base) {
    __builtin_amdgcn_global_load_lds(
        (const __attribute__((address_space(1))) unsigned int*)(unsigned long long)g,
        (__attribute__((address_space(3))) unsigned int*)(unsigned)(unsigned long long)lds_uniform_base,
        16, 0, 0);
}

__global__ void cvt_x(const float* __restrict__ x, unsigned short* __restrict__ xb) {
    int i = blockIdx.x * 256 + threadIdx.x;
    float4 v = ((const float4*)x)[i];
    ushort4 o;
    o.x = f2b(v.x); o.y = f2b(v.y); o.z = f2b(v.z); o.w = f2b(v.w);
    ((ushort4*)xb)[i] = o;
}

// W fp32 [1024 k][1024 n] -> wt bf16 [z][1024 n][1024 k]; z: 0=Wk 1=Wq 2=Wv
__global__ void transpose_w(const float* __restrict__ w0, const float* __restrict__ w1,
                            const float* __restrict__ w2, unsigned short* __restrict__ wt) {
    const float* W = (blockIdx.z == 0) ? w0 : (blockIdx.z == 1) ? w1 : w2;
    __shared__ float t[32][33];
    int k0 = blockIdx.y * 32, n0 = blockIdx.x * 32;
    int tx = threadIdx.x, ty = threadIdx.y; // (32,8)
#pragma unroll
    for (int i = 0; i < 4; i++)
        t[ty * 4 + i][tx] = W[(size_t)(k0 + ty * 4 + i) * 1024 + n0 + tx];
    __syncthreads();
    unsigned short* out = wt + (size_t)blockIdx.z * 1024 * 1024;
#pragma unroll
    for (int i = 0; i < 4; i++)
        out[(size_t)(n0 + ty * 4 + i) * 1024 + k0 + tx] = f2b(t[tx][ty * 4 + i]);
}

// NT GEMM: C[m][n] = alpha * sum_k A[m][k]*B[n][k] + bias[n]
// MODE 0: bf16 out [m][n] (ldc=N).  MODE 1: bf16 transposed per-batch [b][n][s] (S=2048).
// MODE 2: fp32 out [m][n].
template <int MODE>
__global__ __launch_bounds__(256, 2) void gemm_nt(
    const unsigned short* __restrict__ A, const unsigned short* __restrict__ Bm,
    void* __restrict__ Cv, const float* __restrict__ bias,
    int N, int K, long long sA, long long sB, long long sC, float alpha) {
    __shared__ unsigned short As[128 * 32];
    __shared__ unsigned short Bs[128 * 32];
    const int tid = threadIdx.x;
    const int wave = tid >> 6, lane = tid & 63;
    const int m0 = blockIdx.y * 128, n0 = blockIdx.x * 128;
    const long long z = blockIdx.z;
    A += z * sA;
    Bm += z * sB;
    const int wm = wave >> 1, wn = wave & 1;
    f32x4 acc[4][4];
#pragma unroll
    for (int i = 0; i < 4; i++)
#pragma unroll
        for (int j = 0; j < 4; j++) acc[i][j] = (f32x4){0.f, 0.f, 0.f, 0.f};

    const int l16 = lane & 15;
    const int lk = (lane >> 4) << 3; // k-offset 0,8,16,24

    for (int k0 = 0; k0 < K; k0 += 32) {
#pragma unroll
        for (int j = 0; j < 2; j++) {
            int cid = tid + j * 256;          // 0..511 chunks of 8 bf16
            int row = cid >> 2, kk = (cid & 3) << 3;
            gload16(A + (size_t)(m0 + row) * K + k0 + kk,
                    (char*)As + wave * 1024 + j * 4096);
            gload16(Bm + (size_t)(n0 + row) * K + k0 + kk,
                    (char*)Bs + wave * 1024 + j * 4096);
        }
        __syncthreads();
        short8 af[4], bf[4];
#pragma unroll
        for (int m = 0; m < 4; m++)
            af[m] = *(const short8*)&As[(wm * 64 + m * 16 + l16) * 32 + lk];
#pragma unroll
        for (int n = 0; n < 4; n++)
            bf[n] = *(const short8*)&Bs[(wn * 64 + n * 16 + l16) * 32 + lk];
#pragma unroll
        for (int m = 0; m < 4; m++)
#pragma unroll
            for (int n = 0; n < 4; n++)
                acc[m][n] = __builtin_amdgcn_mfma_f32_16x16x32_bf16(af[m], bf[n], acc[m][n], 0, 0, 0);
        __syncthreads();
    }

    const int rowb0 = m0 + wm * 64 + ((lane >> 4) << 2);
    const int colb0 = n0 + wn * 64 + l16;
#pragma unroll
    for (int m = 0; m < 4; m++) {
#pragma unroll
        for (int n = 0; n < 4; n++) {
            int col = colb0 + n * 16;
            int rowb = rowb0 + m * 16;
            float bv_ = bias ? bias[col] : 0.f;
            if (MODE == 0) {
                unsigned short* C = (unsigned short*)Cv + z * sC;
#pragma unroll
                for (int i = 0; i < 4; i++)
                    C[(size_t)(rowb + i) * N + col] = f2b(acc[m][n][i] * alpha + bv_);
            } else if (MODE == 2) {
                float* C = (float*)Cv + z * sC;
#pragma unroll
                for (int i = 0; i < 4; i++)
                    C[(size_t)(rowb + i) * N + col] = acc[m][n][i] * alpha + bv_;
            } else {
                int b = rowb >> 11, s = rowb & 2047; // batch, seq (rows i are consecutive s)
                ushort4 pk;
                pk.x = f2b(acc[m][n][0] * alpha + bv_);
                pk.y = f2b(acc[m][n][1] * alpha + bv_);
                pk.z = f2b(acc[m][n][2] * alpha + bv_);
                pk.w = f2b(acc[m][n][3] * alpha + bv_);
                *(ushort4*)((unsigned short*)Cv + (size_t)b * (1024 * 2048) + (size_t)col * 2048 + s) = pk;
            }
        }
    }
}

// in-place row softmax: sc bf16 [8192][2048], fp32 math
__global__ __launch_bounds__(256) void softmax_inplace(unsigned short* __restrict__ sc) {
    const size_t row = blockIdx.x;
    unsigned short* p = sc + row * 2048;
    const int tid = threadIdx.x;
    const int wave = tid >> 6, lane = tid & 63;
    short8 raw = *(const short8*)&p[tid * 8];
    float f[8];
#pragma unroll
    for (int i = 0; i < 8; i++) f[i] = b2f((unsigned short)raw[i]);
    float mx = f[0];
#pragma unroll
    for (int i = 1; i < 8; i++) mx = fmaxf(mx, f[i]);
#pragma unroll
    for (int o = 32; o > 0; o >>= 1) mx = fmaxf(mx, __shfl_xor(mx, o, 64));
    __shared__ float red[8];
    if (lane == 0) red[wave] = mx;
    __syncthreads();
    mx = fmaxf(fmaxf(red[0], red[1]), fmaxf(red[2], red[3]));
    float e[8], s = 0.f;
#pragma unroll
    for (int i = 0; i < 8; i++) { e[i] = __expf(f[i] - mx); s += e[i]; }
#pragma unroll
    for (int o = 32; o > 0; o >>= 1) s += __shfl_xor(s, o, 64);
    if (lane == 0) red[4 + wave] = s;
    __syncthreads();
    s = (red[4] + red[5]) + (red[6] + red[7]);
    float r = 1.0f / s;
    short8 outv;
#pragma unroll
    for (int i = 0; i < 8; i++) outv[i] = (short)f2b(e[i] * r);
    *(short8*)&p[tid * 8] = outv;
}

extern "C" void kernel_launch(void* const* d_in, const int* in_sizes, int n_in,
                              void* d_out, int out_size, void* d_ws, size_t ws_size,
                              hipStream_t stream) {
    const float* x  = (const float*)d_in[0];
    const float* Wk = (const float*)d_in[1];
    const float* bk = (const float*)d_in[2];
    const float* Wq = (const float*)d_in[3];
    const float* bq = (const float*)d_in[4];
    const float* Wv = (const float*)d_in[5];
    const float* bv = (const float*)d_in[6];
    float* out = (float*)d_out;

    char* ws = (char*)d_ws;
    unsigned short* xb  = (unsigned short*)(ws);
    unsigned short* wt  = (unsigned short*)(ws + 16777216);
    unsigned short* kb  = (unsigned short*)(ws + 23068672);
    unsigned short* qb  = (unsigned short*)(ws + 39845888);
    unsigned short* vtb = (unsigned short*)(ws + 56623104);
    unsigned short* sc  = (unsigned short*)(ws + 73400320);

    cvt_x<<<8192, 256, 0, stream>>>(x, xb);
    transpose_w<<<dim3(32, 32, 3), dim3(32, 8), 0, stream>>>(Wk, Wq, Wv, wt);

    // projections: M=8192, N=1024, K=1024
    gemm_nt<0><<<dim3(8, 64, 1), 256, 0, stream>>>(xb, wt + 0 * 1048576, kb, bk,
                                                   1024, 1024, 0, 0, 0, 1.f);
    gemm_nt<0><<<dim3(8, 64, 1), 256, 0, stream>>>(xb, wt + 1 * 1048576, qb, bq,
                                                   1024, 1024, 0, 0, 0, 1.f);
    gemm_nt<1><<<dim3(8, 64, 1), 256, 0, stream>>>(xb, wt + 2 * 1048576, vtb, bv,
                                                   1024, 1024, 0, 0, 0, 1.f);

    // scores: per batch M=N=2048, K=1024, alpha=1/sqrt(1024)
    gemm_nt<0><<<dim3(16, 16, 4), 256, 0, stream>>>(qb, kb, sc, nullptr,
                                                    2048, 1024,
                                                    2048LL * 1024, 2048LL * 1024, 2048LL * 2048,
                                                    0.03125f);
    softmax_inplace<<<8192, 256, 0, stream>>>(sc);

    // PV: per batch M=2048 (q), N=1024 (d), K=2048 (s)
    gemm_nt<2><<<dim3(8, 16, 4), 256, 0, stream>>>(sc, vtb, out, nullptr,
                                                   1024, 2048,
                                                   2048LL * 2048, 1024LL * 2048, 2048LL * 1024,
                                                   1.f);
}

// Round 4
// 294.616 us; speedup vs baseline: 1.0301x; 1.0301x over previous
//
#include <hip/hip_runtime.h>
#include <hip/hip_bf16.h>

// B=4, S=2048, D=1024 attention. bf16 MFMA, fp32 accum.
// Round 3: 256-row tiles, BK=64, 8 waves/512 thr, double-buffered LDS with
// T3-minimum 2-phase schedule (stage next || compute cur, 1 barrier/K-tile),
// T1 bijective XCD swizzle. All GEMMs exactly 256 blocks (1/CU).
//
// ws layout (bytes):
//   xb   @ 0         : bf16 [8192][1024]
//   wt   @ 16777216  : bf16 [3][1024][1024]  ([n][k], order k,q,v)
//   kb   @ 23068672  : bf16 [4][2048][1024]
//   qb   @ 39845888  : bf16 [4][2048][1024]
//   vtb  @ 56623104  : bf16 [4][1024][2048]  (per-batch transposed V)
//   sc   @ 73400320  : bf16 [4][2048][2048]  (scores, softmaxed in place)

typedef __attribute__((ext_vector_type(8))) short short8;
typedef __attribute__((ext_vector_type(4))) float f32x4;

__device__ __forceinline__ unsigned short f2b(float f) {
    unsigned u = __builtin_bit_cast(unsigned, f);
    unsigned r = 0x7FFFu + ((u >> 16) & 1u);
    return (unsigned short)((u + r) >> 16);
}
__device__ __forceinline__ float b2f(unsigned short h) {
    return __builtin_bit_cast(float, ((unsigned)h) << 16);
}

__device__ __forceinline__ void gload16(const void* g, void* lds_uniform_base) {
    __builtin_amdgcn_global_load_lds(
        (const __attribute__((address_space(1))) unsigned int*)(unsigned long long)g,
        (__attribute__((address_space(3))) unsigned int*)(unsigned)(unsigned long long)lds_uniform_base,
        16, 0, 0);
}

__global__ void cvt_x(const float* __restrict__ x, unsigned short* __restrict__ xb) {
    int i = blockIdx.x * 256 + threadIdx.x;
    float4 v = ((const float4*)x)[i];
    ushort4 o;
    o.x = f2b(v.x); o.y = f2b(v.y); o.z = f2b(v.z); o.w = f2b(v.w);
    ((ushort4*)xb)[i] = o;
}

__global__ void transpose_w(const float* __restrict__ w0, const float* __restrict__ w1,
                            const float* __restrict__ w2, unsigned short* __restrict__ wt) {
    const float* W = (blockIdx.z == 0) ? w0 : (blockIdx.z == 1) ? w1 : w2;
    __shared__ float t[32][33];
    int k0 = blockIdx.y * 32, n0 = blockIdx.x * 32;
    int tx = threadIdx.x, ty = threadIdx.y; // (32,8)
#pragma unroll
    for (int i = 0; i < 4; i++)
        t[ty * 4 + i][tx] = W[(size_t)(k0 + ty * 4 + i) * 1024 + n0 + tx];
    __syncthreads();
    unsigned short* out = wt + (size_t)blockIdx.z * 1024 * 1024;
#pragma unroll
    for (int i = 0; i < 4; i++)
        out[(size_t)(n0 + ty * 4 + i) * 1024 + k0 + tx] = f2b(t[tx][ty * 4 + i]);
}

// NT GEMM, BM=256 fixed, BN in {128,256}. C[m][n] = alpha*sum_k A[m][k]B[n][k] + bias[n]
// MODE 0: bf16 [m][n]. MODE 1: bf16 per-batch transposed [b][n][s], S=2048. MODE 2: fp32 [m][n].
template <int BN, int MODE>
__global__ __launch_bounds__(512, 2) void gemm2(
    const unsigned short* __restrict__ A, const unsigned short* __restrict__ Bm,
    void* __restrict__ Cv, const float* __restrict__ bias,
    int N, int K, long long sA, long long sB, long long sC, float alpha) {
    constexpr int FN = BN / 64; // n-fragments per wave (2 or 4)
    __shared__ unsigned short As[2][256 * 64];
    __shared__ unsigned short Bs[2][BN * 64];
    const int tid = threadIdx.x;
    const int wave = tid >> 6, lane = tid & 63;

    // T1: bijective XCD swizzle (m204) over linear block id
    const int gx = gridDim.x, gy = gridDim.y;
    const int nwg = gx * gy * (int)gridDim.z;
    const int orig = blockIdx.x + gx * (blockIdx.y + gy * blockIdx.z);
    const int q8 = nwg >> 3, r8 = nwg & 7;
    const int xcd = orig & 7, sub = orig >> 3;
    const int wg = (xcd < r8 ? xcd * (q8 + 1) : r8 * (q8 + 1) + (xcd - r8) * q8) + sub;
    const int bx = wg % gx;
    const int tmp = wg / gx;
    const int by = tmp % gy, bz = tmp / gy;

    const int m0 = by * 256, n0 = bx * BN;
    A += (long long)bz * sA;
    Bm += (long long)bz * sB;

    const int wm = wave >> 2, wn = wave & 3; // 2 x 4 waves
    const int l16 = lane & 15;
    const int lk = (lane >> 4) << 3;

    f32x4 acc[8][FN];
#pragma unroll
    for (int m = 0; m < 8; m++)
#pragma unroll
        for (int n = 0; n < FN; n++) acc[m][n] = (f32x4){0.f, 0.f, 0.f, 0.f};

    auto STAGE = [&](int buf, int t) {
        const int k0 = t << 6;
#pragma unroll
        for (int j = 0; j < 4; j++) { // A: 256x64 = 32KB = 4 x 8KB issues
            int cid = tid + j * 512;
            int row = cid >> 3, kk = (cid & 7) << 3;
            gload16(A + (size_t)(m0 + row) * K + k0 + kk,
                    (char*)&As[buf][0] + wave * 1024 + j * 8192);
        }
#pragma unroll
        for (int j = 0; j < FN; j++) { // B: BNx64
            int cid = tid + j * 512;
            int row = cid >> 3, kk = (cid & 7) << 3;
            gload16(Bm + (size_t)(n0 + row) * K + k0 + kk,
                    (char*)&Bs[buf][0] + wave * 1024 + j * 8192);
        }
    };

    const int nt = K >> 6;
    int cur = 0;
    STAGE(0, 0);
    __syncthreads();
    for (int t = 0; t < nt; ++t) {
        if (t + 1 < nt) STAGE(cur ^ 1, t + 1); // issue next-tile loads (overlap w/ MFMA)
#pragma unroll
        for (int ks = 0; ks < 2; ks++) {
            short8 af[8], bf[FN];
#pragma unroll
            for (int m = 0; m < 8; m++)
                af[m] = *(const short8*)&As[cur][(wm * 128 + m * 16 + l16) * 64 + ks * 32 + lk];
#pragma unroll
            for (int n = 0; n < FN; n++)
                bf[n] = *(const short8*)&Bs[cur][(wn * (BN / 4) + n * 16 + l16) * 64 + ks * 32 + lk];
#pragma unroll
            for (int m = 0; m < 8; m++)
#pragma unroll
                for (int n = 0; n < FN; n++)
                    acc[m][n] = __builtin_amdgcn_mfma_f32_16x16x32_bf16(af[m], bf[n], acc[m][n], 0, 0, 0);
        }
        __syncthreads(); // drains staged loads (vmcnt0) + read-complete fence
        cur ^= 1;
    }

    const int rowb0 = m0 + wm * 128 + ((lane >> 4) << 2);
    const int colb0 = n0 + wn * (BN / 4) + l16;
#pragma unroll
    for (int m = 0; m < 8; m++) {
#pragma unroll
        for (int n = 0; n < FN; n++) {
            int col = colb0 + n * 16;
            int rowb = rowb0 + m * 16;
            float bv_ = bias ? bias[col] : 0.f;
            if (MODE == 0) {
                unsigned short* C = (unsigned short*)Cv + (long long)bz * sC;
#pragma unroll
                for (int i = 0; i < 4; i++)
                    C[(size_t)(rowb + i) * N + col] = f2b(acc[m][n][i] * alpha + bv_);
            } else if (MODE == 2) {
                float* C = (float*)Cv + (long long)bz * sC;
#pragma unroll
                for (int i = 0; i < 4; i++)
                    C[(size_t)(rowb + i) * N + col] = acc[m][n][i] * alpha + bv_;
            } else {
                int b = rowb >> 11, s = rowb & 2047; // 4 consecutive s -> ushort4
                ushort4 pk;
                pk.x = f2b(acc[m][n][0] * alpha + bv_);
                pk.y = f2b(acc[m][n][1] * alpha + bv_);
                pk.z = f2b(acc[m][n][2] * alpha + bv_);
                pk.w = f2b(acc[m][n][3] * alpha + bv_);
                *(ushort4*)((unsigned short*)Cv + (size_t)b * (1024 * 2048) + (size_t)col * 2048 + s) = pk;
            }
        }
    }
}

// in-place row softmax: sc bf16 [8192][2048], fp32 math
__global__ __launch_bounds__(256) void softmax_inplace(unsigned short* __restrict__ sc) {
    const size_t row = blockIdx.x;
    unsigned short* p = sc + row * 2048;
    const int tid = threadIdx.x;
    const int wave = tid >> 6, lane = tid & 63;
    short8 raw = *(const short8*)&p[tid * 8];
    float f[8];
#pragma unroll
    for (int i = 0; i < 8; i++) f[i] = b2f((unsigned short)raw[i]);
    float mx = f[0];
#pragma unroll
    for (int i = 1; i < 8; i++) mx = fmaxf(mx, f[i]);
#pragma unroll
    for (int o = 32; o > 0; o >>= 1) mx = fmaxf(mx, __shfl_xor(mx, o, 64));
    __shared__ float red[8];
    if (lane == 0) red[wave] = mx;
    __syncthreads();
    mx = fmaxf(fmaxf(red[0], red[1]), fmaxf(red[2], red[3]));
    float e[8], s = 0.f;
#pragma unroll
    for (int i = 0; i < 8; i++) { e[i] = __expf(f[i] - mx); s += e[i]; }
#pragma unroll
    for (int o = 32; o > 0; o >>= 1) s += __shfl_xor(s, o, 64);
    if (lane == 0) red[4 + wave] = s;
    __syncthreads();
    s = (red[4] + red[5]) + (red[6] + red[7]);
    float r = 1.0f / s;
    short8 outv;
#pragma unroll
    for (int i = 0; i < 8; i++) outv[i] = (short)f2b(e[i] * r);
    *(short8*)&p[tid * 8] = outv;
}

extern "C" void kernel_launch(void* const* d_in, const int* in_sizes, int n_in,
                              void* d_out, int out_size, void* d_ws, size_t ws_size,
                              hipStream_t stream) {
    const float* x  = (const float*)d_in[0];
    const float* Wk = (const float*)d_in[1];
    const float* bk = (const float*)d_in[2];
    const float* Wq = (const float*)d_in[3];
    const float* bq = (const float*)d_in[4];
    const float* Wv = (const float*)d_in[5];
    const float* bv = (const float*)d_in[6];
    float* out = (float*)d_out;

    char* ws = (char*)d_ws;
    unsigned short* xb  = (unsigned short*)(ws);
    unsigned short* wt  = (unsigned short*)(ws + 16777216);
    unsigned short* kb  = (unsigned short*)(ws + 23068672);
    unsigned short* qb  = (unsigned short*)(ws + 39845888);
    unsigned short* vtb = (unsigned short*)(ws + 56623104);
    unsigned short* sc  = (unsigned short*)(ws + 73400320);

    cvt_x<<<8192, 256, 0, stream>>>(x, xb);
    transpose_w<<<dim3(32, 32, 3), dim3(32, 8), 0, stream>>>(Wk, Wq, Wv, wt);

    // projections: M=8192, N=1024, K=1024 — 256x128 tiles, grid 8x32 = 256 blocks
    gemm2<128, 0><<<dim3(8, 32, 1), 512, 0, stream>>>(xb, wt + 0 * 1048576, kb, bk,
                                                      1024, 1024, 0, 0, 0, 1.f);
    gemm2<128, 0><<<dim3(8, 32, 1), 512, 0, stream>>>(xb, wt + 1 * 1048576, qb, bq,
                                                      1024, 1024, 0, 0, 0, 1.f);
    gemm2<128, 1><<<dim3(8, 32, 1), 512, 0, stream>>>(xb, wt + 2 * 1048576, vtb, bv,
                                                      1024, 1024, 0, 0, 0, 1.f);

    // scores: per batch 2048x2048, K=1024 — 256x256 tiles, grid 8x8x4 = 256 blocks
    gemm2<256, 0><<<dim3(8, 8, 4), 512, 0, stream>>>(qb, kb, sc, nullptr,
                                                     2048, 1024,
                                                     2048LL * 1024, 2048LL * 1024, 2048LL * 2048,
                                                     0.03125f);
    softmax_inplace<<<8192, 256, 0, stream>>>(sc);

    // PV: per batch M=2048, N=1024, K=2048 — 256x128 tiles, grid 8x8x4 = 256 blocks
    gemm2<128, 2><<<dim3(8, 8, 4), 512, 0, stream>>>(sc, vtb, out, nullptr,
                                                     1024, 2048,
                                                     2048LL * 2048, 1024LL * 2048, 2048LL * 1024,
                                                     1.f);
}